// Round 1
// baseline (451.902 us; speedup 1.0000x reference)
//
#include <hip/hip_runtime.h>
#include <hip/hip_bf16.h>
#include <cstdint>
#include <cstddef>

#define NN 8192
#define FIN 128
#define FOUT 64

typedef __attribute__((ext_vector_type(8))) short short8;
typedef __attribute__((ext_vector_type(4))) float f32x4;

__device__ __forceinline__ unsigned short f32_to_bf16_bits(float f) {
    union { float f; uint32_t u; } c; c.f = f;
    uint32_t u = c.u;
    u += 0x7fffu + ((u >> 16) & 1u);   // RNE
    return (unsigned short)(u >> 16);
}

// Kernel 1: Wh = x @ W^T (bf16, stored transposed [f][i]); Wh1 = Wh@a1; Wh2 = Wh@a2
__global__ __launch_bounds__(256) void gat_prep(
    const float* __restrict__ x, const float* __restrict__ W,
    const float* __restrict__ a, unsigned short* __restrict__ WhT,
    float* __restrict__ Wh1, float* __restrict__ Wh2)
{
    const int t    = threadIdx.x;
    const int f    = t & 63;        // lane = feature
    const int iloc = t >> 6;        // wave = local row
    const int i    = blockIdx.x * 4 + iloc;

    const float4* x4 = (const float4*)(x + (size_t)i * FIN);  // wave-uniform
    const float4* w4 = (const float4*)(W + (size_t)f * FIN);

    float acc = 0.f;
#pragma unroll
    for (int k = 0; k < FIN / 4; ++k) {
        float4 xv = x4[k];
        float4 wv = w4[k];
        acc += xv.x * wv.x + xv.y * wv.y + xv.z * wv.z + xv.w * wv.w;
    }

    WhT[(size_t)f * NN + i] = f32_to_bf16_bits(acc);

    float r1 = acc * a[f];
    float r2 = acc * a[64 + f];
#pragma unroll
    for (int m = 1; m < 64; m <<= 1) {
        r1 += __shfl_xor(r1, m, 64);
        r2 += __shfl_xor(r2, m, 64);
    }
    if (f == 0) { Wh1[i] = r1; Wh2[i] = r2; }
}

// Kernel 2 (fused): 512 blocks x 512 threads (8 waves). Each block owns a
// 16-row panel and the FULL j range (8192). Wave w covers j-strips
// [w*32 + tt*256, +32) for tt=0..31. Per lane: build P in MFMA A-fragment
// layout, 4x mfma 16x16x32 bf16 against WhT fragments.
//   - adj/Wh2: 2-deep software pipeline (HBM latency ~900cy; issue-to-use
//     is now ~2 full iterations).
//   - WhT (1 MB, L2-resident) + loaded just-in-time each iteration: the
//     CALC/pack VALU work sits between issue and the MFMA use.
//   - epilogue: cross-wave LDS reduce -> normalize -> ELU -> final out.
//     (kernel 3 and the 8 MB Cpart/Tpart round trip are eliminated.)
__global__ __launch_bounds__(512, 4) void gat_attn(
    const int* __restrict__ adj, const unsigned short* __restrict__ WhT,
    const float* __restrict__ Wh1, const float* __restrict__ Wh2,
    float* __restrict__ out)
{
    __shared__ float lds_C[8][16][68];   // +4 pad: 2-way (free) bank aliasing
    __shared__ float lds_tot[8][16];

    const int tid  = threadIdx.x;
    const int wave = tid >> 6;       // 0..7
    const int lane = tid & 63;
    const int il   = lane & 15;      // A-fragment row (i)
    const int q    = lane >> 4;      // quad -> k offset q*8
    const int i0   = blockIdx.x * 16;
    const int i    = i0 + il;

    const float wh1   = Wh1[i];
    const int   jbase = wave * 32 + q * 8;
    const int* __restrict__ adjrow = adj + (size_t)i * NN;

    const short8* bp0 = (const short8*)(WhT + (size_t)(0  + il) * NN);
    const short8* bp1 = (const short8*)(WhT + (size_t)(16 + il) * NN);
    const short8* bp2 = (const short8*)(WhT + (size_t)(32 + il) * NN);
    const short8* bp3 = (const short8*)(WhT + (size_t)(48 + il) * NN);

    f32x4 acc0 = {0.f, 0.f, 0.f, 0.f};
    f32x4 acc1 = {0.f, 0.f, 0.f, 0.f};
    f32x4 acc2 = {0.f, 0.f, 0.f, 0.f};
    f32x4 acc3 = {0.f, 0.f, 0.f, 0.f};
    float tot0 = 0.f, tot1 = 0.f;

    // ---- pipeline prologue: load iters 0 and 1 (2-deep) ----
    int4   aA0 = *(const int4*)(adjrow + jbase);
    int4   aA1 = *(const int4*)(adjrow + jbase + 4);
    float4 wA0 = *(const float4*)(Wh2 + jbase);
    float4 wA1 = *(const float4*)(Wh2 + jbase + 4);
    int4   aB0 = *(const int4*)(adjrow + jbase + 256);
    int4   aB1 = *(const int4*)(adjrow + jbase + 260);
    float4 wB0 = *(const float4*)(Wh2 + jbase + 256);
    float4 wB1 = *(const float4*)(Wh2 + jbase + 260);

#pragma unroll 4
    for (int tt = 0; tt < 32; ++tt) {
        // ---- B fragments for THIS iteration (L2-resident, just-in-time) ----
        const int jb = (jbase + (tt << 8)) >> 3;
        short8 b0 = bp0[jb];
        short8 b1 = bp1[jb];
        short8 b2 = bp2[jb];
        short8 b3 = bp3[jb];

        // ---- prefetch iter tt+2 (wraps on last 2 iters; result unused) ----
        const int jn = jbase + (((tt + 2) & 31) << 8);
        const int4   nA0 = *(const int4*)(adjrow + jn);
        const int4   nA1 = *(const int4*)(adjrow + jn + 4);
        const float4 nW0 = *(const float4*)(Wh2 + jn);
        const float4 nW1 = *(const float4*)(Wh2 + jn + 4);

        // ---- compute iter tt ----
        float wv[8];
#define CALC(idx, adjv, wh2v, totv)                                    \
        {                                                              \
            float s = wh1 + (wh2v);                                    \
            float e = fmaxf(s, 0.2f * s);      /* leaky_relu 0.2 */    \
            float v = ((adjv) > 0) ? __expf(e) : 0.f;                  \
            totv += v;                                                 \
            wv[idx] = v;                                               \
        }
        CALC(0, aA0.x, wA0.x, tot0) CALC(1, aA0.y, wA0.y, tot1)
        CALC(2, aA0.z, wA0.z, tot0) CALC(3, aA0.w, wA0.w, tot1)
        CALC(4, aA1.x, wA1.x, tot0) CALC(5, aA1.y, wA1.y, tot1)
        CALC(6, aA1.z, wA1.z, tot0) CALC(7, aA1.w, wA1.w, tot1)
#undef CALC

        // packed RNE f32->bf16 (v_cvt_pk_bf16_f32 on gfx950)
        union { short8 v; __hip_bfloat162 h[4]; } af;
        af.h[0] = __float22bfloat162_rn(float2{wv[0], wv[1]});
        af.h[1] = __float22bfloat162_rn(float2{wv[2], wv[3]});
        af.h[2] = __float22bfloat162_rn(float2{wv[4], wv[5]});
        af.h[3] = __float22bfloat162_rn(float2{wv[6], wv[7]});

        acc0 = __builtin_amdgcn_mfma_f32_16x16x32_bf16(af.v, b0, acc0, 0, 0, 0);
        acc1 = __builtin_amdgcn_mfma_f32_16x16x32_bf16(af.v, b1, acc1, 0, 0, 0);
        acc2 = __builtin_amdgcn_mfma_f32_16x16x32_bf16(af.v, b2, acc2, 0, 0, 0);
        acc3 = __builtin_amdgcn_mfma_f32_16x16x32_bf16(af.v, b3, acc3, 0, 0, 0);

        // ---- rotate 2-deep pipeline registers ----
        aA0 = aB0; aA1 = aB1; wA0 = wB0; wA1 = wB1;
        aB0 = nA0; aB1 = nA1; wB0 = nW0; wB1 = nW1;
    }

    // row-total reduction: lanes {il, il+16, il+32, il+48} hold partials
    float tot = tot0 + tot1;
    tot += __shfl_xor(tot, 16, 64);
    tot += __shfl_xor(tot, 32, 64);
    if (lane < 16) lds_tot[wave][lane] = tot;

    // C/D layout: col = lane&15 (f within tile), row = q*4 + reg (i)
#pragma unroll
    for (int r = 0; r < 4; ++r) {
        lds_C[wave][q * 4 + r][0 * 16 + il] = acc0[r];
        lds_C[wave][q * 4 + r][1 * 16 + il] = acc1[r];
        lds_C[wave][q * 4 + r][2 * 16 + il] = acc2[r];
        lds_C[wave][q * 4 + r][3 * 16 + il] = acc3[r];
    }
    __syncthreads();

    // epilogue: cross-wave reduce, normalize, ELU, final store
#pragma unroll
    for (int e = 0; e < 2; ++e) {
        const int idx = e * 512 + tid;          // over 16*64 outputs
        const int ii = idx >> 6;
        const int ff = idx & 63;
        float s = 0.f;
#pragma unroll
        for (int w = 0; w < 8; ++w) s += lds_C[w][ii][ff];
        float t = lds_tot[0][ii] + lds_tot[1][ii] + lds_tot[2][ii] +
                  lds_tot[3][ii] + lds_tot[4][ii] + lds_tot[5][ii] +
                  lds_tot[6][ii] + lds_tot[7][ii];
        const float p = s / t;
        out[(size_t)(i0 + ii) * FOUT + ff] = (p > 0.f) ? p : (__expf(p) - 1.f);
    }
}

extern "C" void kernel_launch(void* const* d_in, const int* in_sizes, int n_in,
                              void* d_out, int out_size, void* d_ws, size_t ws_size,
                              hipStream_t stream) {
    const float* x   = (const float*)d_in[0];
    const int*   adj = (const int*)d_in[1];
    const float* W   = (const float*)d_in[2];
    const float* a   = (const float*)d_in[3];
    float* out = (float*)d_out;

    char* ws = (char*)d_ws;
    unsigned short* WhT = (unsigned short*)ws;                 // 1 MB @ 0
    float* Wh1   = (float*)(ws + (size_t)1048576);             // 32 KB
    float* Wh2   = (float*)(ws + (size_t)1048576 + 32768);     // 32 KB

    gat_prep<<<dim3(NN / 4), dim3(256), 0, stream>>>(x, W, a, WhT, Wh1, Wh2);
    gat_attn<<<dim3(NN / 16), dim3(512), 0, stream>>>(adj, WhT, Wh1, Wh2, out);
}

// Round 3
// 450.814 us; speedup vs baseline: 1.0024x; 1.0024x over previous
//
#include <hip/hip_runtime.h>
#include <hip/hip_bf16.h>
#include <cstdint>
#include <cstddef>

#define NN 8192
#define FIN 128
#define FOUT 64

typedef __attribute__((ext_vector_type(8))) short short8;
typedef __attribute__((ext_vector_type(4))) float f32x4;

__device__ __forceinline__ unsigned short f32_to_bf16_bits(float f) {
    union { float f; uint32_t u; } c; c.f = f;
    uint32_t u = c.u;
    u += 0x7fffu + ((u >> 16) & 1u);   // RNE
    return (unsigned short)(u >> 16);
}

// Kernel 1: Wh = x @ W^T (bf16, stored transposed [f][i]); Wh1 = Wh@a1; Wh2 = Wh@a2
__global__ __launch_bounds__(256) void gat_prep(
    const float* __restrict__ x, const float* __restrict__ W,
    const float* __restrict__ a, unsigned short* __restrict__ WhT,
    float* __restrict__ Wh1, float* __restrict__ Wh2)
{
    const int t    = threadIdx.x;
    const int f    = t & 63;        // lane = feature
    const int iloc = t >> 6;        // wave = local row
    const int i    = blockIdx.x * 4 + iloc;

    const float4* x4 = (const float4*)(x + (size_t)i * FIN);  // wave-uniform
    const float4* w4 = (const float4*)(W + (size_t)f * FIN);

    float acc = 0.f;
#pragma unroll
    for (int k = 0; k < FIN / 4; ++k) {
        float4 xv = x4[k];
        float4 wv = w4[k];
        acc += xv.x * wv.x + xv.y * wv.y + xv.z * wv.z + xv.w * wv.w;
    }

    WhT[(size_t)f * NN + i] = f32_to_bf16_bits(acc);

    float r1 = acc * a[f];
    float r2 = acc * a[64 + f];
#pragma unroll
    for (int m = 1; m < 64; m <<= 1) {
        r1 += __shfl_xor(r1, m, 64);
        r2 += __shfl_xor(r2, m, 64);
    }
    if (f == 0) { Wh1[i] = r1; Wh2[i] = r2; }
}

// Kernel 2 (fused): 512 blocks x 512 threads (8 waves). Each block owns a
// 16-row panel and the FULL j range (8192). Wave w covers j-strip
// [w*32 + tt*256, +32) for tt=0..31.
// Pipeline discipline (round-1 post-mortem):
//   - adj   : 2-deep prefetch (HBM stream, ~900cy latency -> 2 iters of
//             issue-to-use distance).
//   - Wh2   : 1-deep (32 KB, L2-resident, ~200cy).
//   - B/WhT : 1-deep (L2-resident; round-1's JIT load exposed L2 latency
//             on the MFMA path and regressed — restored to round-0 style).
// Epilogue: cross-wave LDS reduce -> normalize -> ELU -> final store
// (kernel 3 and the 8 MB Cpart/Tpart round trip stay eliminated).
__global__ __launch_bounds__(512, 4) void gat_attn(
    const int* __restrict__ adj, const unsigned short* __restrict__ WhT,
    const float* __restrict__ Wh1, const float* __restrict__ Wh2,
    float* __restrict__ out)
{
    __shared__ float lds_C[8][16][68];   // +4 pad: 2-way (free) bank aliasing
    __shared__ float lds_tot[8][16];

    const int tid  = threadIdx.x;
    const int wave = tid >> 6;       // 0..7
    const int lane = tid & 63;
    const int il   = lane & 15;      // A-fragment row (i)
    const int q    = lane >> 4;      // quad -> k offset q*8
    const int i0   = blockIdx.x * 16;
    const int i    = i0 + il;

    const float wh1   = Wh1[i];
    const int   jbase = wave * 32 + q * 8;
    const int* __restrict__ adjrow = adj + (size_t)i * NN;

    const short8* bp0 = (const short8*)(WhT + (size_t)(0  + il) * NN);
    const short8* bp1 = (const short8*)(WhT + (size_t)(16 + il) * NN);
    const short8* bp2 = (const short8*)(WhT + (size_t)(32 + il) * NN);
    const short8* bp3 = (const short8*)(WhT + (size_t)(48 + il) * NN);

    f32x4 acc0 = {0.f, 0.f, 0.f, 0.f};
    f32x4 acc1 = {0.f, 0.f, 0.f, 0.f};
    f32x4 acc2 = {0.f, 0.f, 0.f, 0.f};
    f32x4 acc3 = {0.f, 0.f, 0.f, 0.f};
    float tot0 = 0.f, tot1 = 0.f;

    // ---- pipeline prologue ----
    // adj 2-deep: iters 0 and 1
    int4   aA0 = *(const int4*)(adjrow + jbase);
    int4   aA1 = *(const int4*)(adjrow + jbase + 4);
    int4   aB0 = *(const int4*)(adjrow + jbase + 256);
    int4   aB1 = *(const int4*)(adjrow + jbase + 260);
    // Wh2 1-deep: iter 0
    float4 wA0 = *(const float4*)(Wh2 + jbase);
    float4 wA1 = *(const float4*)(Wh2 + jbase + 4);
    // B 1-deep: iter 0
    int jb0 = jbase >> 3;
    short8 b0 = bp0[jb0];
    short8 b1 = bp1[jb0];
    short8 b2 = bp2[jb0];
    short8 b3 = bp3[jb0];

#pragma unroll 2
    for (int tt = 0; tt < 32; ++tt) {
        // ---- prefetch adj for iter tt+2 (wraps; result unused on tail) ----
        const int jn2 = jbase + (((tt + 2) & 31) << 8);
        const int4   nA0 = *(const int4*)(adjrow + jn2);
        const int4   nA1 = *(const int4*)(adjrow + jn2 + 4);

        // ---- prefetch Wh2 + B for iter tt+1 ----
        const int jn1 = jbase + (((tt + 1) & 31) << 8);
        const float4 nW0 = *(const float4*)(Wh2 + jn1);
        const float4 nW1 = *(const float4*)(Wh2 + jn1 + 4);
        const int jnb = jn1 >> 3;
        const short8 nb0 = bp0[jnb];
        const short8 nb1 = bp1[jnb];
        const short8 nb2 = bp2[jnb];
        const short8 nb3 = bp3[jnb];

        // ---- compute iter tt ----
        float wv[8];
#define CALC(idx, adjv, wh2v, totv)                                    \
        {                                                              \
            float s = wh1 + (wh2v);                                    \
            float e = fmaxf(s, 0.2f * s);      /* leaky_relu 0.2 */    \
            float v = ((adjv) > 0) ? __expf(e) : 0.f;                  \
            totv += v;                                                 \
            wv[idx] = v;                                               \
        }
        CALC(0, aA0.x, wA0.x, tot0) CALC(1, aA0.y, wA0.y, tot1)
        CALC(2, aA0.z, wA0.z, tot0) CALC(3, aA0.w, wA0.w, tot1)
        CALC(4, aA1.x, wA1.x, tot0) CALC(5, aA1.y, wA1.y, tot1)
        CALC(6, aA1.z, wA1.z, tot0) CALC(7, aA1.w, wA1.w, tot1)
#undef CALC

        // packed RNE f32->bf16 (v_cvt_pk_bf16_f32 on gfx950)
        union { short8 v; __hip_bfloat162 h[4]; } af;
        af.h[0] = __float22bfloat162_rn(float2{wv[0], wv[1]});
        af.h[1] = __float22bfloat162_rn(float2{wv[2], wv[3]});
        af.h[2] = __float22bfloat162_rn(float2{wv[4], wv[5]});
        af.h[3] = __float22bfloat162_rn(float2{wv[6], wv[7]});

        acc0 = __builtin_amdgcn_mfma_f32_16x16x32_bf16(af.v, b0, acc0, 0, 0, 0);
        acc1 = __builtin_amdgcn_mfma_f32_16x16x32_bf16(af.v, b1, acc1, 0, 0, 0);
        acc2 = __builtin_amdgcn_mfma_f32_16x16x32_bf16(af.v, b2, acc2, 0, 0, 0);
        acc3 = __builtin_amdgcn_mfma_f32_16x16x32_bf16(af.v, b3, acc3, 0, 0, 0);

        // ---- rotate pipeline registers ----
        aA0 = aB0; aA1 = aB1;          // adj: 2-deep shift
        aB0 = nA0; aB1 = nA1;
        wA0 = nW0; wA1 = nW1;          // Wh2: 1-deep
        b0 = nb0; b1 = nb1; b2 = nb2; b3 = nb3;   // B: 1-deep
    }

    // row-total reduction: lanes {il, il+16, il+32, il+48} hold partials
    float tot = tot0 + tot1;
    tot += __shfl_xor(tot, 16, 64);
    tot += __shfl_xor(tot, 32, 64);
    if (lane < 16) lds_tot[wave][lane] = tot;

    // C/D layout: col = lane&15 (f within tile), row = q*4 + reg (i)
#pragma unroll
    for (int r = 0; r < 4; ++r) {
        lds_C[wave][q * 4 + r][0 * 16 + il] = acc0[r];
        lds_C[wave][q * 4 + r][1 * 16 + il] = acc1[r];
        lds_C[wave][q * 4 + r][2 * 16 + il] = acc2[r];
        lds_C[wave][q * 4 + r][3 * 16 + il] = acc3[r];
    }
    __syncthreads();

    // epilogue: cross-wave reduce, normalize, ELU, final store
#pragma unroll
    for (int e = 0; e < 2; ++e) {
        const int idx = e * 512 + tid;          // over 16*64 outputs
        const int ii = idx >> 6;
        const int ff = idx & 63;
        float s = 0.f;
#pragma unroll
        for (int w = 0; w < 8; ++w) s += lds_C[w][ii][ff];
        float t = lds_tot[0][ii] + lds_tot[1][ii] + lds_tot[2][ii] +
                  lds_tot[3][ii] + lds_tot[4][ii] + lds_tot[5][ii] +
                  lds_tot[6][ii] + lds_tot[7][ii];
        const float p = s / t;
        out[(size_t)(i0 + ii) * FOUT + ff] = (p > 0.f) ? p : (__expf(p) - 1.f);
    }
}

extern "C" void kernel_launch(void* const* d_in, const int* in_sizes, int n_in,
                              void* d_out, int out_size, void* d_ws, size_t ws_size,
                              hipStream_t stream) {
    const float* x   = (const float*)d_in[0];
    const int*   adj = (const int*)d_in[1];
    const float* W   = (const float*)d_in[2];
    const float* a   = (const float*)d_in[3];
    float* out = (float*)d_out;

    char* ws = (char*)d_ws;
    unsigned short* WhT = (unsigned short*)ws;                 // 1 MB @ 0
    float* Wh1   = (float*)(ws + (size_t)1048576);             // 32 KB
    float* Wh2   = (float*)(ws + (size_t)1048576 + 32768);     // 32 KB

    gat_prep<<<dim3(NN / 4), dim3(256), 0, stream>>>(x, W, a, WhT, Wh1, Wh2);
    gat_attn<<<dim3(NN / 16), dim3(512), 0, stream>>>(adj, WhT, Wh1, Wh2, out);
}

// Round 7
// 430.255 us; speedup vs baseline: 1.0503x; 1.0478x over previous
//
#include <hip/hip_runtime.h>
#include <hip/hip_bf16.h>
#include <cstdint>
#include <cstddef>

#define NN 8192
#define FIN 128
#define FOUT 64

typedef __attribute__((ext_vector_type(8))) short short8;
typedef __attribute__((ext_vector_type(4))) float f32x4;

__device__ __forceinline__ unsigned short f32_to_bf16_bits(float f) {
    union { float f; uint32_t u; } c; c.f = f;
    uint32_t u = c.u;
    u += 0x7fffu + ((u >> 16) & 1u);   // RNE
    return (unsigned short)(u >> 16);
}

// Kernel 1: Wh = x @ W^T (bf16, stored transposed [f][i]); Wh1 = Wh@a1; Wh2 = Wh@a2
__global__ __launch_bounds__(256) void gat_prep(
    const float* __restrict__ x, const float* __restrict__ W,
    const float* __restrict__ a, unsigned short* __restrict__ WhT,
    float* __restrict__ Wh1, float* __restrict__ Wh2)
{
    const int t    = threadIdx.x;
    const int f    = t & 63;        // lane = feature
    const int iloc = t >> 6;        // wave = local row
    const int i    = blockIdx.x * 4 + iloc;

    const float4* x4 = (const float4*)(x + (size_t)i * FIN);  // wave-uniform
    const float4* w4 = (const float4*)(W + (size_t)f * FIN);

    float acc = 0.f;
#pragma unroll
    for (int k = 0; k < FIN / 4; ++k) {
        float4 xv = x4[k];
        float4 wv = w4[k];
        acc += xv.x * wv.x + xv.y * wv.y + xv.z * wv.z + xv.w * wv.w;
    }

    WhT[(size_t)f * NN + i] = f32_to_bf16_bits(acc);

    float r1 = acc * a[f];
    float r2 = acc * a[64 + f];
#pragma unroll
    for (int m = 1; m < 64; m <<= 1) {
        r1 += __shfl_xor(r1, m, 64);
        r2 += __shfl_xor(r2, m, 64);
    }
    if (f == 0) { Wh1[i] = r1; Wh2[i] = r2; }
}

// Kernel 2 (fused): 512 blocks x 512 threads (8 waves). Each block owns a
// 16-row panel and the FULL j range (8192). Wave w covers j-strip
// [w*32 + tt*256, +32) for tt=0..31.
//
// Register-pressure discipline (round-3 post-mortem): rounds 1/3 timed
// identically (452/451) despite different loop schedules -> spill-bound,
// not schedule-bound. Peak live state must stay under the 128-VGPR cap of
// __launch_bounds__(512,4). Therefore: 1-deep prefetch on ALL streams
// (adj, Wh2, B) exactly as the 424us split baseline, unroll 1 pinned,
// packed cvt (fewer temporaries). Estimated peak ~108 VGPR.
__global__ __launch_bounds__(512, 4) void gat_attn(
    const int* __restrict__ adj, const unsigned short* __restrict__ WhT,
    const float* __restrict__ Wh1, const float* __restrict__ Wh2,
    float* __restrict__ out)
{
    __shared__ float lds_C[8][16][68];   // +4 pad: 2-way (free) bank aliasing
    __shared__ float lds_tot[8][16];

    const int tid  = threadIdx.x;
    const int wave = tid >> 6;       // 0..7
    const int lane = tid & 63;
    const int il   = lane & 15;      // A-fragment row (i)
    const int q    = lane >> 4;      // quad -> k offset q*8
    const int i0   = blockIdx.x * 16;
    const int i    = i0 + il;

    const float wh1   = Wh1[i];
    const int   jbase = wave * 32 + q * 8;
    const int* __restrict__ adjrow = adj + (size_t)i * NN;

    const short8* bp0 = (const short8*)(WhT + (size_t)(0  + il) * NN);
    const short8* bp1 = (const short8*)(WhT + (size_t)(16 + il) * NN);
    const short8* bp2 = (const short8*)(WhT + (size_t)(32 + il) * NN);
    const short8* bp3 = (const short8*)(WhT + (size_t)(48 + il) * NN);

    f32x4 acc0 = {0.f, 0.f, 0.f, 0.f};
    f32x4 acc1 = {0.f, 0.f, 0.f, 0.f};
    f32x4 acc2 = {0.f, 0.f, 0.f, 0.f};
    f32x4 acc3 = {0.f, 0.f, 0.f, 0.f};
    float tot0 = 0.f, tot1 = 0.f;

    // ---- pipeline prologue: load iter 0 (1-deep on every stream) ----
    int4   av0 = *(const int4*)(adjrow + jbase);
    int4   av1 = *(const int4*)(adjrow + jbase + 4);
    float4 w20 = *(const float4*)(Wh2 + jbase);
    float4 w21 = *(const float4*)(Wh2 + jbase + 4);
    int jb0 = jbase >> 3;
    short8 b0 = bp0[jb0];
    short8 b1 = bp1[jb0];
    short8 b2 = bp2[jb0];
    short8 b3 = bp3[jb0];

#pragma unroll 1
    for (int tt = 0; tt < 32; ++tt) {
        // ---- prefetch iter tt+1 (wraps on last iter; result unused) ----
        const int jn = jbase + (((tt + 1) & 31) << 8);   // stride 256/iter
        const int4   nav0 = *(const int4*)(adjrow + jn);
        const int4   nav1 = *(const int4*)(adjrow + jn + 4);
        const float4 nw20 = *(const float4*)(Wh2 + jn);
        const float4 nw21 = *(const float4*)(Wh2 + jn + 4);
        const int jnb = jn >> 3;
        const short8 nb0 = bp0[jnb];
        const short8 nb1 = bp1[jnb];
        const short8 nb2 = bp2[jnb];
        const short8 nb3 = bp3[jnb];

        // ---- compute iter tt ----
        float wv[8];
#define CALC(idx, adjv, wh2v, totv)                                    \
        {                                                              \
            float s = wh1 + (wh2v);                                    \
            float e = fmaxf(s, 0.2f * s);      /* leaky_relu 0.2 */    \
            float v = ((adjv) > 0) ? __expf(e) : 0.f;                  \
            totv += v;                                                 \
            wv[idx] = v;                                               \
        }
        CALC(0, av0.x, w20.x, tot0) CALC(1, av0.y, w20.y, tot1)
        CALC(2, av0.z, w20.z, tot0) CALC(3, av0.w, w20.w, tot1)
        CALC(4, av1.x, w21.x, tot0) CALC(5, av1.y, w21.y, tot1)
        CALC(6, av1.z, w21.z, tot0) CALC(7, av1.w, w21.w, tot1)
#undef CALC

        // packed RNE f32->bf16 (v_cvt_pk_bf16_f32 on gfx950)
        union { short8 v; __hip_bfloat162 h[4]; } af;
        af.h[0] = __float22bfloat162_rn(float2{wv[0], wv[1]});
        af.h[1] = __float22bfloat162_rn(float2{wv[2], wv[3]});
        af.h[2] = __float22bfloat162_rn(float2{wv[4], wv[5]});
        af.h[3] = __float22bfloat162_rn(float2{wv[6], wv[7]});

        acc0 = __builtin_amdgcn_mfma_f32_16x16x32_bf16(af.v, b0, acc0, 0, 0, 0);
        acc1 = __builtin_amdgcn_mfma_f32_16x16x32_bf16(af.v, b1, acc1, 0, 0, 0);
        acc2 = __builtin_amdgcn_mfma_f32_16x16x32_bf16(af.v, b2, acc2, 0, 0, 0);
        acc3 = __builtin_amdgcn_mfma_f32_16x16x32_bf16(af.v, b3, acc3, 0, 0, 0);

        // ---- rotate pipeline registers (1-deep) ----
        av0 = nav0; av1 = nav1; w20 = nw20; w21 = nw21;
        b0 = nb0; b1 = nb1; b2 = nb2; b3 = nb3;
    }

    // row-total reduction: lanes {il, il+16, il+32, il+48} hold partials
    float tot = tot0 + tot1;
    tot += __shfl_xor(tot, 16, 64);
    tot += __shfl_xor(tot, 32, 64);
    if (lane < 16) lds_tot[wave][lane] = tot;

    // C/D layout: col = lane&15 (f within tile), row = q*4 + reg (i)
#pragma unroll
    for (int r = 0; r < 4; ++r) {
        lds_C[wave][q * 4 + r][0 * 16 + il] = acc0[r];
        lds_C[wave][q * 4 + r][1 * 16 + il] = acc1[r];
        lds_C[wave][q * 4 + r][2 * 16 + il] = acc2[r];
        lds_C[wave][q * 4 + r][3 * 16 + il] = acc3[r];
    }
    __syncthreads();

    // epilogue: cross-wave reduce, normalize, ELU, final store
#pragma unroll
    for (int e = 0; e < 2; ++e) {
        const int idx = e * 512 + tid;          // over 16*64 outputs
        const int ii = idx >> 6;
        const int ff = idx & 63;
        float s = 0.f;
#pragma unroll
        for (int w = 0; w < 8; ++w) s += lds_C[w][ii][ff];
        float t = lds_tot[0][ii] + lds_tot[1][ii] + lds_tot[2][ii] +
                  lds_tot[3][ii] + lds_tot[4][ii] + lds_tot[5][ii] +
                  lds_tot[6][ii] + lds_tot[7][ii];
        const float p = s / t;
        out[(size_t)(i0 + ii) * FOUT + ff] = (p > 0.f) ? p : (__expf(p) - 1.f);
    }
}

extern "C" void kernel_launch(void* const* d_in, const int* in_sizes, int n_in,
                              void* d_out, int out_size, void* d_ws, size_t ws_size,
                              hipStream_t stream) {
    const float* x   = (const float*)d_in[0];
    const int*   adj = (const int*)d_in[1];
    const float* W   = (const float*)d_in[2];
    const float* a   = (const float*)d_in[3];
    float* out = (float*)d_out;

    char* ws = (char*)d_ws;
    unsigned short* WhT = (unsigned short*)ws;                 // 1 MB @ 0
    float* Wh1   = (float*)(ws + (size_t)1048576);             // 32 KB
    float* Wh2   = (float*)(ws + (size_t)1048576 + 32768);     // 32 KB

    gat_prep<<<dim3(NN / 4), dim3(256), 0, stream>>>(x, W, a, WhT, Wh1, Wh2);
    gat_attn<<<dim3(NN / 16), dim3(512), 0, stream>>>(adj, WhT, Wh1, Wh2, out);
}